// Round 4
// baseline (374.027 us; speedup 1.0000x reference)
//
#include <hip/hip_runtime.h>
#include <math.h>

static constexpr int BATCH = 32;
static constexpr int SEQ   = 4096;
static constexpr int HID   = 1024;
static constexpr int PSTRIDE = HID + 8;   // ctx[1024] + m + l (+pad, keeps 16B alignment)

// ws layout: [0,128) counters (one int per batch), [512, ...) partials
static constexpr size_t WS_PARTIALS_OFF = 512;

// -------- Fused single kernel: scores + online-softmax context partials,
// with a last-block-per-batch epilogue doing the cross-chunk combine. --------
// grid = BATCH*NCHUNK blocks, 256 threads (4 waves).
// __launch_bounds__(256,3): ~168 VGPR budget so the compiler can rotate
// registers and software-pipeline the pair loop itself (R3 lesson: a hand
// double-buffer under the 128-cap spills and is 2x SLOWER).
template<int NCHUNK>
__global__ __launch_bounds__(256, 3)
void attn_fused(const float* __restrict__ enc,
                const float* __restrict__ dec,
                float* __restrict__ weights,    // [B,S]: raw scores then normalized in-place
                float* __restrict__ partials,   // [B*NCHUNK][PSTRIDE]
                int* __restrict__ counters,     // [B], zeroed before launch
                float* __restrict__ out_ctx)    // [B,H]
{
    constexpr int RC    = SEQ / NCHUNK;   // rows per chunk
    constexpr int RPW   = RC / 4;         // rows per wave
    constexpr int NPAIR = RPW / 2;        // row-pairs per wave

    const int b     = blockIdx.x / NCHUNK;
    const int chunk = blockIdx.x % NCHUNK;
    const int tid   = threadIdx.x;
    const int w     = tid >> 6;
    const int lane  = tid & 63;

    __shared__ float s_dec[HID];
    __shared__ float s_ctx[4][HID];
    __shared__ float s_m[4], s_l[4];

    // stage dec[b] (4 KB) then keep this lane's 16-float fragment in registers
    ((float4*)s_dec)[tid] = ((const float4*)(dec + (size_t)b * HID))[tid];
    __syncthreads();
    const float4* sd = (const float4*)s_dec;
    const float4 d0 = sd[lane], d1 = sd[lane + 64], d2 = sd[lane + 128], d3 = sd[lane + 192];

    float m = -INFINITY, l = 0.f;
    float4 c0 = make_float4(0.f, 0.f, 0.f, 0.f);
    float4 c1 = c0, c2 = c0, c3 = c0;

    const int row0 = chunk * RC + w * RPW;
    const float4* base = (const float4*)(enc + ((size_t)b * SEQ + row0) * HID);
    float* sout = weights + (size_t)b * SEQ + row0;

    #pragma unroll 2
    for (int r = 0; r < NPAIR; ++r) {
        const float4* rpA = base + (size_t)(2 * r) * (HID / 4);
        const float4* rpB = rpA + (HID / 4);
        const float4 a0 = rpA[lane];
        const float4 a1 = rpA[lane + 64];
        const float4 a2 = rpA[lane + 128];
        const float4 a3 = rpA[lane + 192];
        const float4 b0 = rpB[lane];
        const float4 b1 = rpB[lane + 64];
        const float4 b2 = rpB[lane + 128];
        const float4 b3 = rpB[lane + 192];

        // treed dot partials: 4 independent 4-FMA chains each, then 2 adds
        float tA0 = a0.x*d0.x + a0.y*d0.y + a0.z*d0.z + a0.w*d0.w;
        float tA1 = a1.x*d1.x + a1.y*d1.y + a1.z*d1.z + a1.w*d1.w;
        float tA2 = a2.x*d2.x + a2.y*d2.y + a2.z*d2.z + a2.w*d2.w;
        float tA3 = a3.x*d3.x + a3.y*d3.y + a3.z*d3.z + a3.w*d3.w;
        float tB0 = b0.x*d0.x + b0.y*d0.y + b0.z*d0.z + b0.w*d0.w;
        float tB1 = b1.x*d1.x + b1.y*d1.y + b1.z*d1.z + b1.w*d1.w;
        float tB2 = b2.x*d2.x + b2.y*d2.y + b2.z*d2.z + b2.w*d2.w;
        float tB3 = b3.x*d3.x + b3.y*d3.y + b3.z*d3.z + b3.w*d3.w;
        float tA = (tA0 + tA1) + (tA2 + tA3);
        float tB = (tB0 + tB1) + (tB2 + tB3);

        // two independent 6-step reduce chains, interleaved
        #pragma unroll
        for (int off = 32; off > 0; off >>= 1) {
            tA += __shfl_xor(tA, off, 64);
            tB += __shfl_xor(tB, off, 64);
        }

        if (lane == 0) {
            float2 sc2; sc2.x = tA; sc2.y = tB;
            *(float2*)(sout + 2 * r) = sc2;      // raw scores; normalized in epilogue
        }

        const float mn = fmaxf(m, fmaxf(tA, tB));
        if (mn > m) {                            // wave-uniform, rare after warm-up
            const float sc = __expf(m - mn);     // m=-inf first time -> 0
            l *= sc;
            c0.x*=sc; c0.y*=sc; c0.z*=sc; c0.w*=sc;
            c1.x*=sc; c1.y*=sc; c1.z*=sc; c1.w*=sc;
            c2.x*=sc; c2.y*=sc; c2.z*=sc; c2.w*=sc;
            c3.x*=sc; c3.y*=sc; c3.z*=sc; c3.w*=sc;
            m = mn;
        }
        const float pA = __expf(tA - m);
        const float pB = __expf(tB - m);
        l += pA + pB;
        c0.x += pA*a0.x + pB*b0.x; c0.y += pA*a0.y + pB*b0.y;
        c0.z += pA*a0.z + pB*b0.z; c0.w += pA*a0.w + pB*b0.w;
        c1.x += pA*a1.x + pB*b1.x; c1.y += pA*a1.y + pB*b1.y;
        c1.z += pA*a1.z + pB*b1.z; c1.w += pA*a1.w + pB*b1.w;
        c2.x += pA*a2.x + pB*b2.x; c2.y += pA*a2.y + pB*b2.y;
        c2.z += pA*a2.z + pB*b2.z; c2.w += pA*a2.w + pB*b2.w;
        c3.x += pA*a3.x + pB*b3.x; c3.y += pA*a3.y + pB*b3.y;
        c3.z += pA*a3.z + pB*b3.z; c3.w += pA*a3.w + pB*b3.w;
    }

    // ---- combine the 4 waves of this block ----
    if (lane == 0) { s_m[w] = m; s_l[w] = l; }
    __syncthreads();
    const float mg = fmaxf(fmaxf(s_m[0], s_m[1]), fmaxf(s_m[2], s_m[3]));
    const float f  = __expf(m - mg);   // wave-uniform
    float4* sc4 = (float4*)s_ctx[w];
    float4 t0 = c0, t1 = c1, t2 = c2, t3 = c3;
    t0.x*=f; t0.y*=f; t0.z*=f; t0.w*=f;
    t1.x*=f; t1.y*=f; t1.z*=f; t1.w*=f;
    t2.x*=f; t2.y*=f; t2.z*=f; t2.w*=f;
    t3.x*=f; t3.y*=f; t3.z*=f; t3.w*=f;
    sc4[lane]       = t0;
    sc4[lane + 64]  = t1;
    sc4[lane + 128] = t2;
    sc4[lane + 192] = t3;
    __syncthreads();

    float lb = 0.f;
    #pragma unroll
    for (int i = 0; i < 4; ++i) lb += s_l[i] * __expf(s_m[i] - mg);

    float* pout = partials + (size_t)(b * NCHUNK + chunk) * PSTRIDE;
    const float4 v0 = ((const float4*)s_ctx[0])[tid];
    const float4 v1 = ((const float4*)s_ctx[1])[tid];
    const float4 v2 = ((const float4*)s_ctx[2])[tid];
    const float4 v3 = ((const float4*)s_ctx[3])[tid];
    float4 sum;
    sum.x = (v0.x + v1.x) + (v2.x + v3.x);
    sum.y = (v0.y + v1.y) + (v2.y + v3.y);
    sum.z = (v0.z + v1.z) + (v2.z + v3.z);
    sum.w = (v0.w + v1.w) + (v2.w + v3.w);
    ((float4*)pout)[tid] = sum;
    if (tid == 0) { pout[HID] = mg; pout[HID + 1] = lb; }

    // ---- last-block-per-batch epilogue (device-scope release/acquire) ----
    __threadfence();                       // release: partials + raw scores visible
    __shared__ int s_islast;
    if (tid == 0) {
        const int prev = atomicAdd(&counters[b], 1);
        s_islast = (prev == NCHUNK - 1);
    }
    __syncthreads();
    if (!s_islast) return;
    __threadfence();                       // acquire: see other blocks' writes

    __shared__ float sm2[NCHUNK], sl2[NCHUNK];
    if (tid < NCHUNK) {
        const float* p = partials + (size_t)(b * NCHUNK + tid) * PSTRIDE;
        sm2[tid] = p[HID];
        sl2[tid] = p[HID + 1];
    }
    __syncthreads();

    float mgf = -INFINITY;
    #pragma unroll
    for (int c = 0; c < NCHUNK; ++c) mgf = fmaxf(mgf, sm2[c]);
    float lgf = 0.f;
    #pragma unroll
    for (int c = 0; c < NCHUNK; ++c) lgf += sl2[c] * __expf(sm2[c] - mgf);
    const float inv = 1.f / lgf;

    // context: one float4 per thread (H = 1024 = 256 float4)
    float4 acc = make_float4(0.f, 0.f, 0.f, 0.f);
    #pragma unroll 4
    for (int c = 0; c < NCHUNK; ++c) {
        const float4* p4 = (const float4*)(partials + (size_t)(b * NCHUNK + c) * PSTRIDE);
        const float fc = __expf(sm2[c] - mgf);
        const float4 v = p4[tid];
        acc.x += fc * v.x; acc.y += fc * v.y; acc.z += fc * v.z; acc.w += fc * v.w;
    }
    acc.x *= inv; acc.y *= inv; acc.z *= inv; acc.w *= inv;
    ((float4*)(out_ctx + (size_t)b * HID))[tid] = acc;

    // weights: normalize raw scores in place (SEQ/4 = 1024 float4, 4/thread)
    float4* w4 = (float4*)(weights + (size_t)b * SEQ);
    #pragma unroll
    for (int i = 0; i < SEQ / 4 / 256; ++i) {
        const int idx = i * 256 + tid;
        float4 v = w4[idx];
        v.x = __expf(v.x - mgf) * inv;
        v.y = __expf(v.y - mgf) * inv;
        v.z = __expf(v.z - mgf) * inv;
        v.w = __expf(v.w - mgf) * inv;
        w4[idx] = v;
    }
}

extern "C" void kernel_launch(void* const* d_in, const int* in_sizes, int n_in,
                              void* d_out, int out_size, void* d_ws, size_t ws_size,
                              hipStream_t stream) {
    const float* hidden = (const float*)d_in[0];          // [2, 32, 1024]
    const float* enc    = (const float*)d_in[1];          // [32, 4096, 1024]
    const float* dec    = hidden + (size_t)BATCH * HID;   // hidden[-1] -> [32, 1024]

    float* out     = (float*)d_out;
    float* ctx_out = out;                                 // [32, 1024]
    float* w_out   = out + (size_t)BATCH * HID;           // [32, 4096]

    int*   counters = (int*)d_ws;
    float* partials = (float*)((char*)d_ws + WS_PARTIALS_OFF);

    hipMemsetAsync(counters, 0, BATCH * sizeof(int), stream);

#define LAUNCH_NC(NC)                                                              \
    attn_fused<NC><<<BATCH * NC, 256, 0, stream>>>(enc, dec, w_out, partials,      \
                                                   counters, ctx_out)

    const size_t per_chunk_bytes = (size_t)BATCH * PSTRIDE * sizeof(float);
    const size_t avail = (ws_size > WS_PARTIALS_OFF) ? ws_size - WS_PARTIALS_OFF : 0;
    if      (avail >= 32 * per_chunk_bytes) LAUNCH_NC(32);
    else if (avail >= 16 * per_chunk_bytes) LAUNCH_NC(16);
    else if (avail >=  8 * per_chunk_bytes) LAUNCH_NC(8);
    else if (avail >=  4 * per_chunk_bytes) LAUNCH_NC(4);
    else                                    LAUNCH_NC(2);
#undef LAUNCH_NC
}

// Round 6
// 97.522 us; speedup vs baseline: 3.8353x; 3.8353x over previous
//
#include <hip/hip_runtime.h>
#include <math.h>

static constexpr int BATCH = 32;
static constexpr int SEQ   = 4096;
static constexpr int HID   = 1024;
static constexpr int PSTRIDE = HID + 8;   // ctx[1024] + m + l (+pad, keeps 16B alignment)

typedef float f32x4 __attribute__((ext_vector_type(4)));   // native vector: OK for nontemporal builtins

// -------- Pass 1: fused scores + online-softmax context partials --------
// grid = BATCH*NCHUNK blocks, 256 threads (4 waves).
// R2 structure (known-good 116us): manual 2-row unroll, treed dots,
// interleaved shfl chains. R5 delta: nontemporal loads on the read-once
// enc stream (512 MB) to avoid L2/L3 thrash.
template<int NCHUNK>
__global__ __launch_bounds__(256, 4)
void attn_fused_pass1(const float* __restrict__ enc,
                      const float* __restrict__ dec,
                      float* __restrict__ raw_scores,   // [B,S] = weights region of d_out
                      float* __restrict__ partials)     // [B*NCHUNK][PSTRIDE]
{
    constexpr int RC  = SEQ / NCHUNK;   // rows per chunk
    constexpr int RPW = RC / 4;         // rows per wave
    const int b     = blockIdx.x / NCHUNK;
    const int chunk = blockIdx.x % NCHUNK;
    const int tid   = threadIdx.x;
    const int w     = tid >> 6;
    const int lane  = tid & 63;

    __shared__ float s_dec[HID];
    __shared__ float s_ctx[4][HID];
    __shared__ float s_m[4], s_l[4];

    // stage dec[b] (4 KB) then keep this lane's 16-float fragment in registers
    ((float4*)s_dec)[tid] = ((const float4*)(dec + (size_t)b * HID))[tid];
    __syncthreads();
    const f32x4* sd = (const f32x4*)s_dec;
    const f32x4 d0 = sd[lane], d1 = sd[lane + 64], d2 = sd[lane + 128], d3 = sd[lane + 192];

    float m = -INFINITY, l = 0.f;
    f32x4 c0 = (f32x4)(0.f);
    f32x4 c1 = c0, c2 = c0, c3 = c0;

    const int row0 = chunk * RC + w * RPW;
    const f32x4* base = (const f32x4*)(enc + ((size_t)b * SEQ + row0) * HID);
    float* sout = raw_scores + (size_t)b * SEQ + row0;

    for (int r = 0; r < RPW; r += 2) {
        const f32x4* rpA = base + (size_t)r * (HID / 4);
        const f32x4* rpB = rpA + (HID / 4);
        const f32x4 a0 = __builtin_nontemporal_load(rpA + lane);
        const f32x4 a1 = __builtin_nontemporal_load(rpA + lane + 64);
        const f32x4 a2 = __builtin_nontemporal_load(rpA + lane + 128);
        const f32x4 a3 = __builtin_nontemporal_load(rpA + lane + 192);
        const f32x4 b0 = __builtin_nontemporal_load(rpB + lane);
        const f32x4 b1 = __builtin_nontemporal_load(rpB + lane + 64);
        const f32x4 b2 = __builtin_nontemporal_load(rpB + lane + 128);
        const f32x4 b3 = __builtin_nontemporal_load(rpB + lane + 192);

        // treed dot partials: 4 independent 4-FMA chains each, then 2 adds
        float tA0 = a0.x*d0.x + a0.y*d0.y + a0.z*d0.z + a0.w*d0.w;
        float tA1 = a1.x*d1.x + a1.y*d1.y + a1.z*d1.z + a1.w*d1.w;
        float tA2 = a2.x*d2.x + a2.y*d2.y + a2.z*d2.z + a2.w*d2.w;
        float tA3 = a3.x*d3.x + a3.y*d3.y + a3.z*d3.z + a3.w*d3.w;
        float tB0 = b0.x*d0.x + b0.y*d0.y + b0.z*d0.z + b0.w*d0.w;
        float tB1 = b1.x*d1.x + b1.y*d1.y + b1.z*d1.z + b1.w*d1.w;
        float tB2 = b2.x*d2.x + b2.y*d2.y + b2.z*d2.z + b2.w*d2.w;
        float tB3 = b3.x*d3.x + b3.y*d3.y + b3.z*d3.z + b3.w*d3.w;
        float tA = (tA0 + tA1) + (tA2 + tA3);
        float tB = (tB0 + tB1) + (tB2 + tB3);

        // two independent 6-step reduce chains, interleaved
        #pragma unroll
        for (int off = 32; off > 0; off >>= 1) {
            tA += __shfl_xor(tA, off, 64);
            tB += __shfl_xor(tB, off, 64);
        }

        if (lane == 0) {
            float2 sc2; sc2.x = tA; sc2.y = tB;
            *(float2*)(sout + r) = sc2;      // raw scores; normalized in pass 2
        }

        const float mn = fmaxf(m, fmaxf(tA, tB));
        if (mn > m) {                        // wave-uniform, rare after warm-up
            const float sc = __expf(m - mn); // m=-inf first time -> 0
            l *= sc;
            c0 *= sc; c1 *= sc; c2 *= sc; c3 *= sc;
            m = mn;
        }
        const float pA = __expf(tA - m);
        const float pB = __expf(tB - m);
        l += pA + pB;
        c0 += pA*a0 + pB*b0;
        c1 += pA*a1 + pB*b1;
        c2 += pA*a2 + pB*b2;
        c3 += pA*a3 + pB*b3;
    }

    // ---- combine the 4 waves of this block ----
    if (lane == 0) { s_m[w] = m; s_l[w] = l; }
    __syncthreads();
    const float mg = fmaxf(fmaxf(s_m[0], s_m[1]), fmaxf(s_m[2], s_m[3]));
    const float f  = __expf(m - mg);   // wave-uniform
    f32x4* sc4 = (f32x4*)s_ctx[w];
    sc4[lane]       = c0 * f;
    sc4[lane + 64]  = c1 * f;
    sc4[lane + 128] = c2 * f;
    sc4[lane + 192] = c3 * f;
    __syncthreads();

    float lb = 0.f;
    #pragma unroll
    for (int i = 0; i < 4; ++i) lb += s_l[i] * __expf(s_m[i] - mg);

    float* pout = partials + (size_t)(b * NCHUNK + chunk) * PSTRIDE;
    const f32x4 v0 = ((const f32x4*)s_ctx[0])[tid];
    const f32x4 v1 = ((const f32x4*)s_ctx[1])[tid];
    const f32x4 v2 = ((const f32x4*)s_ctx[2])[tid];
    const f32x4 v3 = ((const f32x4*)s_ctx[3])[tid];
    const f32x4 sum = (v0 + v1) + (v2 + v3);
    ((f32x4*)pout)[tid] = sum;
    if (tid == 0) { pout[HID] = mg; pout[HID + 1] = lb; }
}

// -------- Pass 2: cross-chunk combine + weights normalization --------
// grid = BATCH * 8 blocks; each block redundantly recomputes the cheap
// (m,l) combine; sub-block 0 writes context, all 8 split the weights row.
template<int NCHUNK>
__global__ __launch_bounds__(256)
void attn_pass2(const float* __restrict__ partials,
                float* __restrict__ out_ctx,    // [B,H]
                float* __restrict__ weights)    // [B,S] in-place raw->softmax
{
    const int b   = blockIdx.x >> 3;
    const int sub = blockIdx.x & 7;
    const int tid = threadIdx.x;
    __shared__ float sm[NCHUNK], sl[NCHUNK];
    if (tid < NCHUNK) {
        const float* p = partials + (size_t)(b * NCHUNK + tid) * PSTRIDE;
        sm[tid] = p[HID];
        sl[tid] = p[HID + 1];
    }
    __syncthreads();

    float mg = -INFINITY;
    #pragma unroll
    for (int c = 0; c < NCHUNK; ++c) mg = fmaxf(mg, sm[c]);
    float lg = 0.f;
    #pragma unroll
    for (int c = 0; c < NCHUNK; ++c) lg += sl[c] * __expf(sm[c] - mg);
    const float inv = 1.f / lg;

    if (sub == 0) {
        // context: one float4 per thread (H = 1024 = 256 float4)
        f32x4 acc = (f32x4)(0.f);
        #pragma unroll 4
        for (int c = 0; c < NCHUNK; ++c) {
            const f32x4* p4 = (const f32x4*)(partials + (size_t)(b * NCHUNK + c) * PSTRIDE);
            const float fc = __expf(sm[c] - mg);
            acc += fc * p4[tid];
        }
        acc *= inv;
        ((f32x4*)(out_ctx + (size_t)b * HID))[tid] = acc;
    }

    // weights: normalize raw scores in place, SEQ/8 = 512 per sub-block
    float* wrow = weights + (size_t)b * SEQ;
    const int s0 = sub * (SEQ / 8);
    #pragma unroll
    for (int i = 0; i < SEQ / 8 / 256; ++i) {
        const int s = s0 + i * 256 + tid;
        wrow[s] = __expf(wrow[s] - mg) * inv;
    }
}

extern "C" void kernel_launch(void* const* d_in, const int* in_sizes, int n_in,
                              void* d_out, int out_size, void* d_ws, size_t ws_size,
                              hipStream_t stream) {
    const float* hidden = (const float*)d_in[0];          // [2, 32, 1024]
    const float* enc    = (const float*)d_in[1];          // [32, 4096, 1024]
    const float* dec    = hidden + (size_t)BATCH * HID;   // hidden[-1] -> [32, 1024]

    float* out     = (float*)d_out;
    float* ctx_out = out;                                 // [32, 1024]
    float* w_out   = out + (size_t)BATCH * HID;           // [32, 4096]
    float* partials = (float*)d_ws;

#define LAUNCH_NC(NC)                                                              \
    do {                                                                           \
        attn_fused_pass1<NC><<<BATCH * NC, 256, 0, stream>>>(enc, dec, w_out,      \
                                                             partials);            \
        attn_pass2<NC><<<BATCH * 8, 256, 0, stream>>>(partials, ctx_out, w_out);   \
    } while (0)

    const size_t per_chunk_bytes = (size_t)BATCH * PSTRIDE * sizeof(float);
    if      (ws_size >= 32 * per_chunk_bytes) LAUNCH_NC(32);
    else if (ws_size >= 16 * per_chunk_bytes) LAUNCH_NC(16);
    else if (ws_size >=  8 * per_chunk_bytes) LAUNCH_NC(8);
    else if (ws_size >=  4 * per_chunk_bytes) LAUNCH_NC(4);
    else if (ws_size >=  2 * per_chunk_bytes) LAUNCH_NC(2);
    else                                      LAUNCH_NC(1);
#undef LAUNCH_NC
}